// Round 7
// baseline (50.368 us; speedup 1.0000x reference)
//
#include <hip/hip_runtime.h>

// ---------------------------------------------------------------------------
// Single-kernel SO(3) convolution (LMAX=2). Compile-time real-SH CG table so
// the contraction unrolls into register FMAs. One block (256 thr) per atom:
//   A) coalesced bitmask scan of idx_i -> edge list in LDS (deterministic)
//   B) 2 sub-groups x 128 channels; FULL 1-deep software pipeline: both the
//      x-row (VGPR) and the uniform edge params radial/dir/cutoff (SGPR via
//      readfirstlane'd edge id) are prefetched one edge ahead, so steady
//      state is issue-bound compute with no exposed load latency.
//   C) cross-sub LDS reduce + single coalesced non-atomic write.
// __launch_bounds__(256,4): <=128 VGPR -> 4 blocks/CU -> all atoms co-resident.
// ---------------------------------------------------------------------------

#define SH_N 9
#define NB 128
#define NR 20
#define NSUB 2
#define NT (NSUB * NB)      // 256 threads
#define CAPL 128            // max edges per atom (Poisson(10); max ~28)

namespace cgc {

struct CD { double re, im; };
constexpr CD cmul(CD x, CD y) { return {x.re * y.re - x.im * y.im, x.re * y.im + x.im * y.re}; }
constexpr CD cadd(CD x, CD y) { return {x.re + y.re, x.im + y.im}; }
constexpr CD cconj(CD x) { return {x.re, -x.im}; }

constexpr double FACT[10] = {1., 1., 2., 6., 24., 120., 720., 5040., 40320., 362880.};

constexpr double csqrt(double a) {
    if (a <= 0.0) return 0.0;
    double x = a < 1.0 ? 1.0 : a;
    for (int i = 0; i < 40; ++i) x = 0.5 * (x + a / x);
    return x;
}

constexpr double cg_complex(int l1, int m1, int l2, int m2, int l3, int m3) {
    if (m3 != m1 + m2) return 0.0;
    int dl = l1 > l2 ? l1 - l2 : l2 - l1;
    if (l3 < dl || l3 > l1 + l2) return 0.0;
    double pre = csqrt((2.0 * l3 + 1.0) * FACT[l3 + l1 - l2] * FACT[l3 - l1 + l2]
                       * FACT[l1 + l2 - l3] / FACT[l1 + l2 + l3 + 1]);
    pre = pre * csqrt(FACT[l3 + m3] * FACT[l3 - m3] * FACT[l1 - m1] * FACT[l1 + m1]
                      * FACT[l2 - m2] * FACT[l2 + m2]);
    int kmin = 0;
    if (l2 - l3 - m1 > kmin) kmin = l2 - l3 - m1;
    if (l1 - l3 + m2 > kmin) kmin = l1 - l3 + m2;
    int kmax = l1 + l2 - l3;
    if (l1 - m1 < kmax) kmax = l1 - m1;
    if (l2 + m2 < kmax) kmax = l2 + m2;
    double s = 0.0;
    for (int k = kmin; k <= kmax; ++k) {
        double term = 1.0 / (FACT[k] * FACT[l1 + l2 - l3 - k] * FACT[l1 - m1 - k]
                             * FACT[l2 + m2 - k] * FACT[l3 - l2 + m1 + k] * FACT[l3 - l1 - m2 + k]);
        s += (k & 1) ? -term : term;
    }
    return pre * s;
}

struct U5 { CD m[5][5]; };
constexpr U5 u_c2r(int l) {
    U5 u{};
    const double isq = csqrt(0.5);
    u.m[l][l] = {1.0, 0.0};
    for (int mm = 1; mm <= l; ++mm) {
        double sgn = (mm & 1) ? -1.0 : 1.0;
        u.m[l + mm][l + mm] = {sgn * isq, 0.0};
        u.m[l + mm][l - mm] = {isq, 0.0};
        u.m[l - mm][l - mm] = {0.0, isq};
        u.m[l - mm][l + mm] = {0.0, -sgn * isq};
    }
    return u;
}

struct CGTab { float v[SH_N][SH_N][SH_N]; };   // [i1_dir][i2_x][i_out]

constexpr CGTab build_cg() {
    CGTab t{};
    for (int l1 = 0; l1 <= 2; ++l1)
    for (int l2 = 0; l2 <= 2; ++l2)
    for (int l3 = 0; l3 <= 2; ++l3) {
        int dl = l1 > l2 ? l1 - l2 : l2 - l1;
        if (((l1 + l2 + l3) & 1) || l3 < dl || l3 > l1 + l2) continue;
        U5 U1 = u_c2r(l1), U2 = u_c2r(l2), U3 = u_c2r(l3);
        const int n1 = 2 * l1 + 1, n2 = 2 * l2 + 1, n3 = 2 * l3 + 1;
        double blk[5][5][5] = {};
        for (int a = 0; a < n1; ++a)
        for (int b = 0; b < n2; ++b) {
            int m1 = a - l1, m2 = b - l2, m3 = m1 + m2;
            if (m3 < -l3 || m3 > l3) continue;
            blk[a][b][m3 + l3] = cg_complex(l1, m1, l2, m2, l3, m3);
        }
        for (int i = 0; i < n1; ++i)
        for (int j = 0; j < n2; ++j)
        for (int k = 0; k < n3; ++k) {
            CD s{0.0, 0.0};
            for (int a = 0; a < n1; ++a) {
                if (U1.m[i][a].re == 0.0 && U1.m[i][a].im == 0.0) continue;
                for (int b = 0; b < n2; ++b) {
                    if (U2.m[j][b].re == 0.0 && U2.m[j][b].im == 0.0) continue;
                    int m3 = (a - l1) + (b - l2);
                    if (m3 < -l3 || m3 > l3) continue;
                    double B = blk[a][b][m3 + l3];
                    if (B == 0.0) continue;
                    CD u3 = cconj(U3.m[k][m3 + l3]);
                    if (u3.re == 0.0 && u3.im == 0.0) continue;
                    CD term = cmul(cmul(U1.m[i][a], U2.m[j][b]), u3);
                    s = cadd(s, CD{term.re * B, term.im * B});
                }
            }
            double v = s.re;
            if (v < 1e-12 && v > -1e-12) v = 0.0;
            t.v[l1 * l1 + i][l2 * l2 + j][l3 * l3 + k] = (float)v;
        }
    }
    return t;
}

} // namespace cgc

static constexpr cgc::CGTab CGT = cgc::build_cg();

__device__ __forceinline__ float sel_w(int a, float w0, float w1, float w2) {
    return (a == 0) ? w0 : ((a < 4) ? w1 : w2);
}

// Wave-uniform per-edge parameters -> SGPRs (edge id is readfirstlane'd).
struct EP {
    float rad[NR];
    float d[SH_N];
    float cut;
};

__device__ __forceinline__ void load_params(EP& p, int e,
        const float* __restrict__ radial, const float* __restrict__ dir,
        const float* __restrict__ cutoff) {
    const float* rp = radial + (size_t)e * NR;
#pragma unroll
    for (int r = 0; r < NR; ++r) p.rad[r] = rp[r];
    const float* dp = dir + (size_t)e * SH_N;
#pragma unroll
    for (int k = 0; k < SH_N; ++k) p.d[k] = dp[k];
    p.cut = cutoff[e];
}

__device__ __forceinline__ void load_xr(float (&xr)[SH_N], int e,
        const float* __restrict__ x, const int* __restrict__ idx_j, int c) {
    const int aj = idx_j[e];                          // e uniform -> s_load
    const float* xp = x + (size_t)aj * (SH_N * NB) + c;
#pragma unroll
    for (int k = 0; k < SH_N; ++k) xr[k] = xp[k * NB];
}

// Pure compute: radial filter + CG contraction; no memory ops.
__device__ __forceinline__ void comp_edge(
        const EP& p, const float (&xr)[SH_N],
        const float (&wreg)[NR * 3], float b0, float b1, float b2,
        float (&acc)[SH_N]) {
    float a0 = b0, a1 = b1, a2 = b2;
#pragma unroll
    for (int r = 0; r < NR; ++r) {
        const float rv = p.rad[r];
        a0 = fmaf(rv, wreg[r * 3 + 0], a0);
        a1 = fmaf(rv, wreg[r * 3 + 1], a1);
        a2 = fmaf(rv, wreg[r * 3 + 2], a2);
    }
    const float w0 = a0 * p.cut, w1 = a1 * p.cut, w2 = a2 * p.cut;
#pragma unroll
    for (int ai = 0; ai < SH_N; ++ai) {
        const float daw = p.d[ai] * sel_w(ai, w0, w1, w2);
#pragma unroll
        for (int bi = 0; bi < SH_N; ++bi) {
            const float g = daw * xr[bi];
#pragma unroll
            for (int o = 0; o < SH_N; ++o)
                if (CGT.v[ai][bi][o] != 0.0f)
                    acc[o] = fmaf(CGT.v[ai][bi][o], g, acc[o]);
        }
    }
}

// ---------------------------------------------------------------------------

__global__ void __launch_bounds__(NT, 4)
so3_fused_kernel(const float* __restrict__ x,
                 const float* __restrict__ radial,
                 const float* __restrict__ dir,
                 const float* __restrict__ cutoff,
                 const float* __restrict__ Wf,
                 const float* __restrict__ bf,
                 const int* __restrict__ idx_i,
                 const int* __restrict__ idx_j,
                 float* __restrict__ y,
                 int E) {
    const int a    = blockIdx.x;
    const int tid  = threadIdx.x;
    const int sub  = tid >> 7;          // 0..1
    const int c    = tid & (NB - 1);    // basis channel
    const int lane = tid & 63;
    const int wid  = tid >> 6;          // 0..3

    __shared__ int s_list[CAPL];
    __shared__ int s_wsum[NT / 64];
    __shared__ int s_m;

    // Wf column + bias -> registers, reused for every edge of this block
    float wreg[NR * 3];
#pragma unroll
    for (int r = 0; r < NR; ++r)
#pragma unroll
        for (int l = 0; l < 3; ++l)
            wreg[r * 3 + l] = Wf[(r * 3 + l) * NB + c];
    const float b0 = bf[c], b1 = bf[NB + c], b2 = bf[2 * NB + c];

    // ---- phase A: find this atom's edges via coalesced int4 + bitmask ----
    unsigned long long mask = 0ull;
    int cnt = 0;
    const int E4 = E >> 2;
    const bool fast_scan = (4 * ((E4 + NT - 1) / NT) <= 60);
    if (fast_scan) {
        const int4* p4 = (const int4*)idx_i;
        int b = 0;
        for (int k4 = tid; k4 < E4; k4 += NT, ++b) {
            const int4 q = p4[k4];
            unsigned long long h = (unsigned long long)(q.x == a)
                                 | ((unsigned long long)(q.y == a) << 1)
                                 | ((unsigned long long)(q.z == a) << 2)
                                 | ((unsigned long long)(q.w == a) << 3);
            mask |= h << (4 * b);
        }
        const int kt = 4 * E4 + tid;
        if (tid < (E & 3) && kt < E && idx_i[kt] == a)
            mask |= 1ull << (60 + tid);
        cnt = __popcll(mask);
    } else {
        for (int k = tid; k < E; k += NT) cnt += (idx_i[k] == a);
    }

    // block exclusive prefix over cnt
    int v = cnt;
#pragma unroll
    for (int d = 1; d < 64; d <<= 1) {
        int u = __shfl_up(v, d);
        if (lane >= d) v += u;
    }
    if (lane == 63) s_wsum[wid] = v;
    __syncthreads();
    if (tid == 0) {
        int t = 0;
#pragma unroll
        for (int w = 0; w < NT / 64; ++w) { int q = s_wsum[w]; s_wsum[w] = t; t += q; }
        s_m = t;
    }
    __syncthreads();
    int off = s_wsum[wid] + v - cnt;

    if (fast_scan) {
        unsigned long long mm = mask;
        while (mm) {
            const int p = __ffsll(mm) - 1;
            mm &= mm - 1;
            int k;
            if (p >= 60) k = 4 * E4 + (p - 60);
            else         k = 4 * (tid + (p >> 2) * NT) + (p & 3);
            if (off < CAPL) s_list[off] = k;
            ++off;
        }
    } else if (cnt > 0) {
        for (int k = tid; k < E; k += NT)
            if (idx_i[k] == a) { if (off < CAPL) s_list[off] = k; ++off; }
    }
    __syncthreads();
    const int m = (s_m < CAPL) ? s_m : CAPL;

    // ---- phase B: fully pipelined edge loop (params + xr both 1 ahead) ----
    float acc[SH_N];
#pragma unroll
    for (int o = 0; o < SH_N; ++o) acc[o] = 0.f;

    int ie = sub;
    if (ie < m) {
        float xrA[SH_N], xrB[SH_N];
        EP pA, pB;
        {
            const int eA = __builtin_amdgcn_readfirstlane(s_list[ie]);
            load_xr(xrA, eA, x, idx_j, c);
            load_params(pA, eA, radial, dir, cutoff);
        }
        for (;;) {
            int ien = ie + NSUB;
            if (ien < m) {
                const int eB = __builtin_amdgcn_readfirstlane(s_list[ien]);
                load_xr(xrB, eB, x, idx_j, c);          // prefetch next edge
                load_params(pB, eB, radial, dir, cutoff);
                comp_edge(pA, xrA, wreg, b0, b1, b2, acc);
                ie = ien; ien += NSUB;
                if (ien < m) {
                    const int eA = __builtin_amdgcn_readfirstlane(s_list[ien]);
                    load_xr(xrA, eA, x, idx_j, c);
                    load_params(pA, eA, radial, dir, cutoff);
                    comp_edge(pB, xrB, wreg, b0, b1, b2, acc);
                    ie = ien;
                } else {
                    comp_edge(pB, xrB, wreg, b0, b1, b2, acc);
                    break;
                }
            } else {
                comp_edge(pA, xrA, wreg, b0, b1, b2, acc);
                break;
            }
        }
    }

    // ---- phase C: 2-way cross-sub reduce + coalesced write ----
    __shared__ float s_red[NSUB][SH_N * NB];
#pragma unroll
    for (int o = 0; o < SH_N; ++o) s_red[sub][o * NB + c] = acc[o];
    __syncthreads();
    float* yo = y + (size_t)a * (SH_N * NB);
    for (int oc = tid; oc < SH_N * NB; oc += NT)
        yo[oc] = s_red[0][oc] + s_red[1][oc];
}

// ---------------------------------------------------------------------------

extern "C" void kernel_launch(void* const* d_in, const int* in_sizes, int n_in,
                              void* d_out, int out_size, void* d_ws, size_t ws_size,
                              hipStream_t stream) {
    const float* x      = (const float*)d_in[0];
    const float* radial = (const float*)d_in[1];
    const float* dir    = (const float*)d_in[2];
    const float* cutoff = (const float*)d_in[3];
    const float* Wf     = (const float*)d_in[4];
    const float* bf     = (const float*)d_in[5];
    const int*   idx_i  = (const int*)d_in[6];
    const int*   idx_j  = (const int*)d_in[7];
    float* y = (float*)d_out;
    const int E = in_sizes[6];
    const int n_atoms = out_size / (SH_N * NB);

    so3_fused_kernel<<<n_atoms, NT, 0, stream>>>(x, radial, dir, cutoff, Wf, bf,
                                                 idx_i, idx_j, y, E);
}

// Round 8
// 31.036 us; speedup vs baseline: 1.6229x; 1.6229x over previous
//
#include <hip/hip_runtime.h>

// ---------------------------------------------------------------------------
// Two-kernel SO(3) convolution (LMAX=2).
//  K1 radial_kernel: W[e][l][c] = (radial[e]@Wf + bf)[l,c] * cutoff[e] -> d_ws.
//     wreg[60] lives in VGPRs here safely (nothing else competes).
//  K2 so3_atom_kernel: one block (512 thr) per atom; bitmask scan of idx_i ->
//     edge list in LDS; 4 sub-groups x 128 channels; per-edge state is only
//     {xr[9], w[3]} per lane + d[9] uniform -> ~55 VGPR, no spill; 1-deep
//     software pipeline; cross-sub LDS reduce; single coalesced write.
// Compile-time real-SH CG table so the contraction unrolls into register FMAs.
// ---------------------------------------------------------------------------

#define SH_N 9
#define NB 128
#define NR 20
#define NSUB 4
#define NT2 (NSUB * NB)     // 512 threads (atom kernel)
#define CAPL 128            // max edges per atom (Poisson(10); max ~28)
#define EB 8                // edges per block in radial kernel

namespace cgc {

struct CD { double re, im; };
constexpr CD cmul(CD x, CD y) { return {x.re * y.re - x.im * y.im, x.re * y.im + x.im * y.re}; }
constexpr CD cadd(CD x, CD y) { return {x.re + y.re, x.im + y.im}; }
constexpr CD cconj(CD x) { return {x.re, -x.im}; }

constexpr double FACT[10] = {1., 1., 2., 6., 24., 120., 720., 5040., 40320., 362880.};

constexpr double csqrt(double a) {
    if (a <= 0.0) return 0.0;
    double x = a < 1.0 ? 1.0 : a;
    for (int i = 0; i < 40; ++i) x = 0.5 * (x + a / x);
    return x;
}

constexpr double cg_complex(int l1, int m1, int l2, int m2, int l3, int m3) {
    if (m3 != m1 + m2) return 0.0;
    int dl = l1 > l2 ? l1 - l2 : l2 - l1;
    if (l3 < dl || l3 > l1 + l2) return 0.0;
    double pre = csqrt((2.0 * l3 + 1.0) * FACT[l3 + l1 - l2] * FACT[l3 - l1 + l2]
                       * FACT[l1 + l2 - l3] / FACT[l1 + l2 + l3 + 1]);
    pre = pre * csqrt(FACT[l3 + m3] * FACT[l3 - m3] * FACT[l1 - m1] * FACT[l1 + m1]
                      * FACT[l2 - m2] * FACT[l2 + m2]);
    int kmin = 0;
    if (l2 - l3 - m1 > kmin) kmin = l2 - l3 - m1;
    if (l1 - l3 + m2 > kmin) kmin = l1 - l3 + m2;
    int kmax = l1 + l2 - l3;
    if (l1 - m1 < kmax) kmax = l1 - m1;
    if (l2 + m2 < kmax) kmax = l2 + m2;
    double s = 0.0;
    for (int k = kmin; k <= kmax; ++k) {
        double term = 1.0 / (FACT[k] * FACT[l1 + l2 - l3 - k] * FACT[l1 - m1 - k]
                             * FACT[l2 + m2 - k] * FACT[l3 - l2 + m1 + k] * FACT[l3 - l1 - m2 + k]);
        s += (k & 1) ? -term : term;
    }
    return pre * s;
}

struct U5 { CD m[5][5]; };
constexpr U5 u_c2r(int l) {
    U5 u{};
    const double isq = csqrt(0.5);
    u.m[l][l] = {1.0, 0.0};
    for (int mm = 1; mm <= l; ++mm) {
        double sgn = (mm & 1) ? -1.0 : 1.0;
        u.m[l + mm][l + mm] = {sgn * isq, 0.0};
        u.m[l + mm][l - mm] = {isq, 0.0};
        u.m[l - mm][l - mm] = {0.0, isq};
        u.m[l - mm][l + mm] = {0.0, -sgn * isq};
    }
    return u;
}

struct CGTab { float v[SH_N][SH_N][SH_N]; };   // [i1_dir][i2_x][i_out]

constexpr CGTab build_cg() {
    CGTab t{};
    for (int l1 = 0; l1 <= 2; ++l1)
    for (int l2 = 0; l2 <= 2; ++l2)
    for (int l3 = 0; l3 <= 2; ++l3) {
        int dl = l1 > l2 ? l1 - l2 : l2 - l1;
        if (((l1 + l2 + l3) & 1) || l3 < dl || l3 > l1 + l2) continue;
        U5 U1 = u_c2r(l1), U2 = u_c2r(l2), U3 = u_c2r(l3);
        const int n1 = 2 * l1 + 1, n2 = 2 * l2 + 1, n3 = 2 * l3 + 1;
        double blk[5][5][5] = {};
        for (int a = 0; a < n1; ++a)
        for (int b = 0; b < n2; ++b) {
            int m1 = a - l1, m2 = b - l2, m3 = m1 + m2;
            if (m3 < -l3 || m3 > l3) continue;
            blk[a][b][m3 + l3] = cg_complex(l1, m1, l2, m2, l3, m3);
        }
        for (int i = 0; i < n1; ++i)
        for (int j = 0; j < n2; ++j)
        for (int k = 0; k < n3; ++k) {
            CD s{0.0, 0.0};
            for (int a = 0; a < n1; ++a) {
                if (U1.m[i][a].re == 0.0 && U1.m[i][a].im == 0.0) continue;
                for (int b = 0; b < n2; ++b) {
                    if (U2.m[j][b].re == 0.0 && U2.m[j][b].im == 0.0) continue;
                    int m3 = (a - l1) + (b - l2);
                    if (m3 < -l3 || m3 > l3) continue;
                    double B = blk[a][b][m3 + l3];
                    if (B == 0.0) continue;
                    CD u3 = cconj(U3.m[k][m3 + l3]);
                    if (u3.re == 0.0 && u3.im == 0.0) continue;
                    CD term = cmul(cmul(U1.m[i][a], U2.m[j][b]), u3);
                    s = cadd(s, CD{term.re * B, term.im * B});
                }
            }
            double v = s.re;
            if (v < 1e-12 && v > -1e-12) v = 0.0;
            t.v[l1 * l1 + i][l2 * l2 + j][l3 * l3 + k] = (float)v;
        }
    }
    return t;
}

} // namespace cgc

static constexpr cgc::CGTab CGT = cgc::build_cg();

__device__ __forceinline__ float sel_w(int a, float w0, float w1, float w2) {
    return (a == 0) ? w0 : ((a < 4) ? w1 : w2);
}

// ---------------------------------------------------------------------------
// K1: per-edge radial filter -> W[e][3][NB] in d_ws. Edges are block-uniform
// so the radial row scalarizes; wreg[60] safely in VGPRs (simple kernel).
// ---------------------------------------------------------------------------

__global__ void __launch_bounds__(NB)
radial_kernel(const float* __restrict__ radial,
              const float* __restrict__ cutoff,
              const float* __restrict__ Wf,
              const float* __restrict__ bf,
              float* __restrict__ W,
              int E) {
    const int c = threadIdx.x;
    float wreg[NR * 3];
#pragma unroll
    for (int r = 0; r < NR; ++r)
#pragma unroll
        for (int l = 0; l < 3; ++l)
            wreg[r * 3 + l] = Wf[r * 3 * NB + l * NB + c];
    const float b0 = bf[c], b1 = bf[NB + c], b2 = bf[2 * NB + c];

    const int e0 = blockIdx.x * EB;
#pragma unroll
    for (int i = 0; i < EB; ++i) {
        const int e = e0 + i;
        if (e >= E) return;
        const float* rad = radial + (size_t)e * NR;   // block-uniform -> s_load
        float a0 = b0, a1 = b1, a2 = b2;
#pragma unroll
        for (int r = 0; r < NR; ++r) {
            const float rv = rad[r];
            a0 = fmaf(rv, wreg[r * 3 + 0], a0);
            a1 = fmaf(rv, wreg[r * 3 + 1], a1);
            a2 = fmaf(rv, wreg[r * 3 + 2], a2);
        }
        const float cut = cutoff[e];
        float* wp = W + (size_t)e * (3 * NB) + c;
        wp[0]       = a0 * cut;
        wp[NB]      = a1 * cut;
        wp[2 * NB]  = a2 * cut;
    }
}

// ---------------------------------------------------------------------------
// K2: atom-centric contraction reading precomputed W.
// ---------------------------------------------------------------------------

struct Ld { float xr[SH_N]; float w0, w1, w2; };

__device__ __forceinline__ void load_edge(Ld& L, float (&d)[SH_N], int e,
        const float* __restrict__ x, const float* __restrict__ W,
        const float* __restrict__ dir, const int* __restrict__ idx_j, int c) {
    const int aj = idx_j[e];                          // e uniform -> s_load
    const float* xp = x + (size_t)aj * (SH_N * NB) + c;
#pragma unroll
    for (int k = 0; k < SH_N; ++k) L.xr[k] = xp[k * NB];
    const float* wp = W + (size_t)e * (3 * NB) + c;
    L.w0 = wp[0]; L.w1 = wp[NB]; L.w2 = wp[2 * NB];
    const float* dp = dir + (size_t)e * SH_N;         // uniform -> s_load
#pragma unroll
    for (int k = 0; k < SH_N; ++k) d[k] = dp[k];
}

__device__ __forceinline__ void comp_edge(const Ld& L, const float (&d)[SH_N],
                                          float (&acc)[SH_N]) {
#pragma unroll
    for (int ai = 0; ai < SH_N; ++ai) {
        const float daw = d[ai] * sel_w(ai, L.w0, L.w1, L.w2);
#pragma unroll
        for (int bi = 0; bi < SH_N; ++bi) {
            const float g = daw * L.xr[bi];
#pragma unroll
            for (int o = 0; o < SH_N; ++o)
                if (CGT.v[ai][bi][o] != 0.0f)
                    acc[o] = fmaf(CGT.v[ai][bi][o], g, acc[o]);
        }
    }
}

__global__ void __launch_bounds__(NT2)
so3_atom_kernel(const float* __restrict__ x,
                const float* __restrict__ W,
                const float* __restrict__ dir,
                const int* __restrict__ idx_i,
                const int* __restrict__ idx_j,
                float* __restrict__ y,
                int E) {
    const int a    = blockIdx.x;
    const int tid  = threadIdx.x;
    const int sub  = tid >> 7;          // 0..3
    const int c    = tid & (NB - 1);    // basis channel
    const int lane = tid & 63;
    const int wid  = tid >> 6;          // 0..7

    __shared__ int s_list[CAPL];
    __shared__ int s_wsum[NT2 / 64];
    __shared__ int s_m;

    // ---- phase A: find this atom's edges via coalesced int4 + bitmask ----
    unsigned long long mask = 0ull;
    int cnt = 0;
    const int E4 = E >> 2;
    const bool fast_scan = (4 * ((E4 + NT2 - 1) / NT2) <= 60);
    if (fast_scan) {
        const int4* p4 = (const int4*)idx_i;
        int b = 0;
        for (int k4 = tid; k4 < E4; k4 += NT2, ++b) {
            const int4 q = p4[k4];
            unsigned long long h = (unsigned long long)(q.x == a)
                                 | ((unsigned long long)(q.y == a) << 1)
                                 | ((unsigned long long)(q.z == a) << 2)
                                 | ((unsigned long long)(q.w == a) << 3);
            mask |= h << (4 * b);
        }
        const int kt = 4 * E4 + tid;
        if (tid < (E & 3) && kt < E && idx_i[kt] == a)
            mask |= 1ull << (60 + tid);
        cnt = __popcll(mask);
    } else {
        for (int k = tid; k < E; k += NT2) cnt += (idx_i[k] == a);
    }

    // block exclusive prefix over cnt
    int v = cnt;
#pragma unroll
    for (int d = 1; d < 64; d <<= 1) {
        int u = __shfl_up(v, d);
        if (lane >= d) v += u;
    }
    if (lane == 63) s_wsum[wid] = v;
    __syncthreads();
    if (tid == 0) {
        int t = 0;
#pragma unroll
        for (int w = 0; w < NT2 / 64; ++w) { int q = s_wsum[w]; s_wsum[w] = t; t += q; }
        s_m = t;
    }
    __syncthreads();
    int off = s_wsum[wid] + v - cnt;

    if (fast_scan) {
        unsigned long long mm = mask;
        while (mm) {
            const int p = __ffsll(mm) - 1;
            mm &= mm - 1;
            int k;
            if (p >= 60) k = 4 * E4 + (p - 60);
            else         k = 4 * (tid + (p >> 2) * NT2) + (p & 3);
            if (off < CAPL) s_list[off] = k;
            ++off;
        }
    } else if (cnt > 0) {
        for (int k = tid; k < E; k += NT2)
            if (idx_i[k] == a) { if (off < CAPL) s_list[off] = k; ++off; }
    }
    __syncthreads();
    const int m = (s_m < CAPL) ? s_m : CAPL;

    // ---- phase B: pipelined edge loop, tiny per-edge state ----
    float acc[SH_N];
#pragma unroll
    for (int o = 0; o < SH_N; ++o) acc[o] = 0.f;

    int ie = sub;
    if (ie < m) {
        Ld LA, LB;
        float dA[SH_N], dB[SH_N];
        {
            const int eA = __builtin_amdgcn_readfirstlane(s_list[ie]);
            load_edge(LA, dA, eA, x, W, dir, idx_j, c);
        }
        for (;;) {
            int ien = ie + NSUB;
            if (ien < m) {
                const int eB = __builtin_amdgcn_readfirstlane(s_list[ien]);
                load_edge(LB, dB, eB, x, W, dir, idx_j, c);   // prefetch
                comp_edge(LA, dA, acc);
                ie = ien; ien += NSUB;
                if (ien < m) {
                    const int eA = __builtin_amdgcn_readfirstlane(s_list[ien]);
                    load_edge(LA, dA, eA, x, W, dir, idx_j, c);
                    comp_edge(LB, dB, acc);
                    ie = ien;
                } else {
                    comp_edge(LB, dB, acc);
                    break;
                }
            } else {
                comp_edge(LA, dA, acc);
                break;
            }
        }
    }

    // ---- phase C: cross-sub reduce + coalesced write ----
    __shared__ float s_red[NSUB][SH_N * NB];
#pragma unroll
    for (int o = 0; o < SH_N; ++o) s_red[sub][o * NB + c] = acc[o];
    __syncthreads();
    float* yo = y + (size_t)a * (SH_N * NB);
    for (int oc = tid; oc < SH_N * NB; oc += NT2)
        yo[oc] = s_red[0][oc] + s_red[1][oc] + s_red[2][oc] + s_red[3][oc];
}

// ---------------------------------------------------------------------------
// Fallback (ws too small): single kernel, radial filter from Wf staged in LDS.
// ---------------------------------------------------------------------------

__global__ void __launch_bounds__(NT2)
so3_atom_kernel_lds(const float* __restrict__ x,
                    const float* __restrict__ radial,
                    const float* __restrict__ dir,
                    const float* __restrict__ cutoff,
                    const float* __restrict__ Wf,
                    const float* __restrict__ bf,
                    const int* __restrict__ idx_i,
                    const int* __restrict__ idx_j,
                    float* __restrict__ y,
                    int E) {
    const int a    = blockIdx.x;
    const int tid  = threadIdx.x;
    const int sub  = tid >> 7;
    const int c    = tid & (NB - 1);
    const int lane = tid & 63;
    const int wid  = tid >> 6;

    __shared__ int s_list[CAPL];
    __shared__ int s_wsum[NT2 / 64];
    __shared__ int s_m;
    __shared__ float s_wf[NR * 3 * NB];

    for (int idx = tid; idx < NR * 3 * NB; idx += NT2) s_wf[idx] = Wf[idx];

    unsigned long long mask = 0ull;
    int cnt = 0;
    const int E4 = E >> 2;
    const bool fast_scan = (4 * ((E4 + NT2 - 1) / NT2) <= 60);
    if (fast_scan) {
        const int4* p4 = (const int4*)idx_i;
        int b = 0;
        for (int k4 = tid; k4 < E4; k4 += NT2, ++b) {
            const int4 q = p4[k4];
            unsigned long long h = (unsigned long long)(q.x == a)
                                 | ((unsigned long long)(q.y == a) << 1)
                                 | ((unsigned long long)(q.z == a) << 2)
                                 | ((unsigned long long)(q.w == a) << 3);
            mask |= h << (4 * b);
        }
        const int kt = 4 * E4 + tid;
        if (tid < (E & 3) && kt < E && idx_i[kt] == a)
            mask |= 1ull << (60 + tid);
        cnt = __popcll(mask);
    } else {
        for (int k = tid; k < E; k += NT2) cnt += (idx_i[k] == a);
    }

    int v = cnt;
#pragma unroll
    for (int d = 1; d < 64; d <<= 1) {
        int u = __shfl_up(v, d);
        if (lane >= d) v += u;
    }
    if (lane == 63) s_wsum[wid] = v;
    __syncthreads();
    if (tid == 0) {
        int t = 0;
#pragma unroll
        for (int w = 0; w < NT2 / 64; ++w) { int q = s_wsum[w]; s_wsum[w] = t; t += q; }
        s_m = t;
    }
    __syncthreads();
    int off = s_wsum[wid] + v - cnt;
    if (fast_scan) {
        unsigned long long mm = mask;
        while (mm) {
            const int p = __ffsll(mm) - 1;
            mm &= mm - 1;
            int k;
            if (p >= 60) k = 4 * E4 + (p - 60);
            else         k = 4 * (tid + (p >> 2) * NT2) + (p & 3);
            if (off < CAPL) s_list[off] = k;
            ++off;
        }
    } else if (cnt > 0) {
        for (int k = tid; k < E; k += NT2)
            if (idx_i[k] == a) { if (off < CAPL) s_list[off] = k; ++off; }
    }
    __syncthreads();
    const int m = (s_m < CAPL) ? s_m : CAPL;

    float acc[SH_N];
#pragma unroll
    for (int o = 0; o < SH_N; ++o) acc[o] = 0.f;
    const float b0 = bf[c], b1 = bf[NB + c], b2 = bf[2 * NB + c];

    for (int ie = sub; ie < m; ie += NSUB) {
        const int e = __builtin_amdgcn_readfirstlane(s_list[ie]);
        const int aj = idx_j[e];
        float xr[SH_N];
        const float* xp = x + (size_t)aj * (SH_N * NB) + c;
#pragma unroll
        for (int k = 0; k < SH_N; ++k) xr[k] = xp[k * NB];
        const float* rad = radial + (size_t)e * NR;
        float a0 = b0, a1 = b1, a2 = b2;
#pragma unroll
        for (int r = 0; r < NR; ++r) {
            const float rv = rad[r];
            a0 = fmaf(rv, s_wf[(r * 3 + 0) * NB + c], a0);
            a1 = fmaf(rv, s_wf[(r * 3 + 1) * NB + c], a1);
            a2 = fmaf(rv, s_wf[(r * 3 + 2) * NB + c], a2);
        }
        const float cut = cutoff[e];
        const float w0 = a0 * cut, w1 = a1 * cut, w2 = a2 * cut;
        const float* dp = dir + (size_t)e * SH_N;
#pragma unroll
        for (int ai = 0; ai < SH_N; ++ai) {
            const float daw = dp[ai] * sel_w(ai, w0, w1, w2);
#pragma unroll
            for (int bi = 0; bi < SH_N; ++bi) {
                const float g = daw * xr[bi];
#pragma unroll
                for (int o = 0; o < SH_N; ++o)
                    if (CGT.v[ai][bi][o] != 0.0f)
                        acc[o] = fmaf(CGT.v[ai][bi][o], g, acc[o]);
            }
        }
    }

    __shared__ float s_red[NSUB][SH_N * NB];
#pragma unroll
    for (int o = 0; o < SH_N; ++o) s_red[sub][o * NB + c] = acc[o];
    __syncthreads();
    float* yo = y + (size_t)a * (SH_N * NB);
    for (int oc = tid; oc < SH_N * NB; oc += NT2)
        yo[oc] = s_red[0][oc] + s_red[1][oc] + s_red[2][oc] + s_red[3][oc];
}

// ---------------------------------------------------------------------------

extern "C" void kernel_launch(void* const* d_in, const int* in_sizes, int n_in,
                              void* d_out, int out_size, void* d_ws, size_t ws_size,
                              hipStream_t stream) {
    const float* x      = (const float*)d_in[0];
    const float* radial = (const float*)d_in[1];
    const float* dir    = (const float*)d_in[2];
    const float* cutoff = (const float*)d_in[3];
    const float* Wf     = (const float*)d_in[4];
    const float* bf     = (const float*)d_in[5];
    const int*   idx_i  = (const int*)d_in[6];
    const int*   idx_j  = (const int*)d_in[7];
    float* y = (float*)d_out;
    const int E = in_sizes[6];
    const int n_atoms = out_size / (SH_N * NB);

    const size_t needW = (size_t)E * 3 * NB * sizeof(float);
    if (ws_size >= needW) {
        float* W = (float*)d_ws;
        radial_kernel<<<(E + EB - 1) / EB, NB, 0, stream>>>(radial, cutoff, Wf, bf, W, E);
        so3_atom_kernel<<<n_atoms, NT2, 0, stream>>>(x, W, dir, idx_i, idx_j, y, E);
    } else {
        so3_atom_kernel_lds<<<n_atoms, NT2, 0, stream>>>(x, radial, dir, cutoff,
                                                         Wf, bf, idx_i, idx_j, y, E);
    }
}